// Round 11
// baseline (1165.256 us; speedup 1.0000x reference)
//
#include <hip/hip_runtime.h>
#include <hip/hip_bf16.h>
#include <cstdint>

#define DIM_   1024
#define H_     16
#define DH_    64
#define INNER_ 1024
#define B_     2
#define I_     2048
#define J_     2048
#define SCALE_ 0.125f

using bf16x8 = __attribute__((ext_vector_type(8))) short;
using f32x4  = __attribute__((ext_vector_type(4))) float;

__device__ __forceinline__ unsigned short f2bf(float f) {
  unsigned int u = __float_as_uint(f);
  u = (u + 0x7FFFu + ((u >> 16) & 1u)) >> 16;
  return (unsigned short)u;
}
__device__ __forceinline__ float bf2f(unsigned short h) {
  return __uint_as_float(((unsigned int)h) << 16);
}

// async global->LDS, 16B per lane; LDS dest is wave-uniform base + lane*16
__device__ __forceinline__ void gld16(const unsigned short* g, unsigned short* l) {
  __builtin_amdgcn_global_load_lds(
      (const __attribute__((address_space(1))) unsigned int*)g,
      (__attribute__((address_space(3))) unsigned int*)l, 16, 0, 0);
}

// ---------------- LayerNorm + cast to bf16 ----------------
__global__ __launch_bounds__(256) void ln_cast_kernel(
    const float* __restrict__ in, const float* __restrict__ g,
    const float* __restrict__ bb, unsigned short* __restrict__ out) {
  int row = blockIdx.x;
  int t = threadIdx.x;
  const float4* rp = (const float4*)(in + (size_t)row * DIM_);
  float4 v = rp[t];
  float s  = v.x + v.y + v.z + v.w;
  float ss = v.x * v.x + v.y * v.y + v.z * v.z + v.w * v.w;
  for (int o = 1; o < 64; o <<= 1) {
    s  += __shfl_xor(s, o, 64);
    ss += __shfl_xor(ss, o, 64);
  }
  __shared__ float ls[4], lss[4];
  int wave = t >> 6, lane = t & 63;
  if (lane == 0) { ls[wave] = s; lss[wave] = ss; }
  __syncthreads();
  s  = ls[0] + ls[1] + ls[2] + ls[3];
  ss = lss[0] + lss[1] + lss[2] + lss[3];
  float mu  = s * (1.0f / DIM_);
  float var = ss * (1.0f / DIM_) - mu * mu;
  float rstd = rsqrtf(var + 1e-5f);
  float4 gv = ((const float4*)g)[t];
  float4 bv = ((const float4*)bb)[t];
  ushort4 o4;
  o4.x = f2bf((v.x - mu) * rstd * gv.x + bv.x);
  o4.y = f2bf((v.y - mu) * rstd * gv.y + bv.y);
  o4.z = f2bf((v.z - mu) * rstd * gv.z + bv.z);
  o4.w = f2bf((v.w - mu) * rstd * gv.w + bv.w);
  ((ushort4*)(out + (size_t)row * DIM_))[t] = o4;
}

// ---------------- transpose + cast f32 -> bf16 ----------------
__global__ __launch_bounds__(256) void transpose_cast_f32(
    const float* __restrict__ in, unsigned short* __restrict__ out, int R, int C) {
  __shared__ float tile[32][33];
  int z = blockIdx.z;
  const float* ip = in + (size_t)z * R * C;
  unsigned short* op = out + (size_t)z * R * C;
  int c0 = blockIdx.x * 32, r0 = blockIdx.y * 32;
  int tx = threadIdx.x, ty = threadIdx.y;
  for (int k = 0; k < 4; k++)
    tile[ty * 4 + k][tx] = ip[(size_t)(r0 + ty * 4 + k) * C + c0 + tx];
  __syncthreads();
  for (int k = 0; k < 4; k++)
    op[(size_t)(c0 + ty * 4 + k) * R + r0 + tx] = f2bf(tile[tx][ty * 4 + k]);
}

// ---------------- transpose bf16 -> bf16 ----------------
__global__ __launch_bounds__(256) void transpose_bf16(
    const unsigned short* __restrict__ in, unsigned short* __restrict__ out, int R, int C) {
  __shared__ unsigned short tile[32][33];
  int z = blockIdx.z;
  const unsigned short* ip = in + (size_t)z * R * C;
  unsigned short* op = out + (size_t)z * R * C;
  int c0 = blockIdx.x * 32, r0 = blockIdx.y * 32;
  int tx = threadIdx.x, ty = threadIdx.y;
  for (int k = 0; k < 4; k++)
    tile[ty * 4 + k][tx] = ip[(size_t)(r0 + ty * 4 + k) * C + c0 + tx];
  __syncthreads();
  for (int k = 0; k < 4; k++)
    op[(size_t)(c0 + ty * 4 + k) * R + r0 + tx] = tile[tx][ty * 4 + k];
}

// ---------------- fused QKV GEMM: m97-style global_load_lds staging ----------------
__global__ __launch_bounds__(256) void gemm_qkv(
    const unsigned short* __restrict__ A0, const unsigned short* __restrict__ A1,
    const unsigned short* __restrict__ Bt0, const unsigned short* __restrict__ Bt1,
    unsigned short* __restrict__ qkO0, unsigned short* __restrict__ vO0,
    unsigned short* __restrict__ qkO1, unsigned short* __restrict__ vO1,
    int M, int K) {
  __shared__ unsigned short As[128 * 32];
  __shared__ unsigned short Bs[128 * 32];
  int z = blockIdx.z;
  const unsigned short* A  = z ? A1 : A0;
  const unsigned short* Bt = z ? Bt1 : Bt0;
  unsigned short* qkO = z ? qkO1 : qkO0;
  unsigned short* vO  = z ? vO1 : vO0;
  int t = threadIdx.x;
  int lane = t & 63, wave = t >> 6;
  int m0 = blockIdx.y * 128, n0 = blockIdx.x * 128;
  int wm = (wave >> 1) * 64, wn = (wave & 1) * 64;
  int l15 = lane & 15, lk = lane >> 4;
  int srow = t >> 2, scol = (t & 3) * 8;
  f32x4 acc[4][4] = {};

  for (int k0 = 0; k0 < K; k0 += 32) {
    gld16(&A[(size_t)(m0 + srow) * K + k0 + scol],       &As[wave * 512]);
    gld16(&A[(size_t)(m0 + srow + 64) * K + k0 + scol],  &As[2048 + wave * 512]);
    gld16(&Bt[(size_t)(n0 + srow) * K + k0 + scol],      &Bs[wave * 512]);
    gld16(&Bt[(size_t)(n0 + srow + 64) * K + k0 + scol], &Bs[2048 + wave * 512]);
    __syncthreads();
    bf16x8 af[4], bfr[4];
#pragma unroll
    for (int mi = 0; mi < 4; mi++) af[mi]  = *(const bf16x8*)&As[(wm + mi * 16 + l15) * 32 + lk * 8];
#pragma unroll
    for (int ni = 0; ni < 4; ni++) bfr[ni] = *(const bf16x8*)&Bs[(wn + ni * 16 + l15) * 32 + lk * 8];
#pragma unroll
    for (int mi = 0; mi < 4; mi++)
#pragma unroll
      for (int ni = 0; ni < 4; ni++)
        acc[mi][ni] = __builtin_amdgcn_mfma_f32_16x16x32_bf16(af[mi], bfr[ni], acc[mi][ni], 0, 0, 0);
    __syncthreads();
  }
  unsigned short* dst = (n0 < 1024) ? qkO : vO;
  int nbase = n0 & 1023;
#pragma unroll
  for (int mi = 0; mi < 4; mi++)
#pragma unroll
    for (int ni = 0; ni < 4; ni++) {
      int col = nbase + wn + ni * 16 + l15;
#pragma unroll
      for (int r = 0; r < 4; r++) {
        int row = m0 + wm + mi * 16 + lk * 4 + r;
        dst[(size_t)row * INNER_ + col] = f2bf(acc[mi][ni][r]);
      }
    }
}

// ---------------- output GEMM: z in {dir1, dir2}, f32 + bias; gload_lds staging ----
__global__ __launch_bounds__(256) void gemm_out(
    const unsigned short* __restrict__ A0, const unsigned short* __restrict__ A1,
    const unsigned short* __restrict__ Bt0, const unsigned short* __restrict__ Bt1,
    const float* __restrict__ bias0, const float* __restrict__ bias1,
    float* __restrict__ C0, float* __restrict__ C1,
    int M, int N, int K) {
  __shared__ unsigned short As[128 * 32];
  __shared__ unsigned short Bs[128 * 32];
  int z = blockIdx.z;
  const unsigned short* A  = z ? A1 : A0;
  const unsigned short* Bt = z ? Bt1 : Bt0;
  const float* bias = z ? bias1 : bias0;
  float* Cout = z ? C1 : C0;
  int t = threadIdx.x;
  int lane = t & 63, wave = t >> 6;
  int m0 = blockIdx.y * 128, n0 = blockIdx.x * 128;
  int wm = (wave >> 1) * 64, wn = (wave & 1) * 64;
  int l15 = lane & 15, lk = lane >> 4;
  int srow = t >> 2, scol = (t & 3) * 8;
  f32x4 acc[4][4] = {};

  for (int k0 = 0; k0 < K; k0 += 32) {
    gld16(&A[(size_t)(m0 + srow) * K + k0 + scol],       &As[wave * 512]);
    gld16(&A[(size_t)(m0 + srow + 64) * K + k0 + scol],  &As[2048 + wave * 512]);
    gld16(&Bt[(size_t)(n0 + srow) * K + k0 + scol],      &Bs[wave * 512]);
    gld16(&Bt[(size_t)(n0 + srow + 64) * K + k0 + scol], &Bs[2048 + wave * 512]);
    __syncthreads();
    bf16x8 af[4], bfr[4];
#pragma unroll
    for (int mi = 0; mi < 4; mi++) af[mi]  = *(const bf16x8*)&As[(wm + mi * 16 + l15) * 32 + lk * 8];
#pragma unroll
    for (int ni = 0; ni < 4; ni++) bfr[ni] = *(const bf16x8*)&Bs[(wn + ni * 16 + l15) * 32 + lk * 8];
#pragma unroll
    for (int mi = 0; mi < 4; mi++)
#pragma unroll
      for (int ni = 0; ni < 4; ni++)
        acc[mi][ni] = __builtin_amdgcn_mfma_f32_16x16x32_bf16(af[mi], bfr[ni], acc[mi][ni], 0, 0, 0);
    __syncthreads();
  }
#pragma unroll
  for (int mi = 0; mi < 4; mi++)
#pragma unroll
    for (int ni = 0; ni < 4; ni++) {
      int col = n0 + wn + ni * 16 + l15;
      float bsv = bias[col];
#pragma unroll
      for (int r = 0; r < 4; r++) {
        int row = m0 + wm + mi * 16 + lk * 4 + r;
        Cout[(size_t)row * N + col] = acc[mi][ni][r] + bsv;
      }
    }
}

// ---------------- stats: both dirs + both b in one launch; 64-i tiles ----------------
__global__ __launch_bounds__(256) void stats_kernel(
    const unsigned short* __restrict__ qk, const unsigned short* __restrict__ ck,
    float* __restrict__ rsum, float* __restrict__ csum, int NQ, int NK) {
  int zz = blockIdx.z;
  int b = zz & 1, dir = zz >> 1;
  const unsigned short* Q  = dir ? ck : qk;
  const unsigned short* Kc = dir ? qk : ck;
  float* out = dir ? csum : rsum;
  int h = blockIdx.y, i0 = blockIdx.x * 64;
  int t = threadIdx.x, lane = t & 63, wave = t >> 6;
  int l15 = lane & 15, lk = lane >> 4;
  const size_t qbase = ((size_t)b * NQ + i0) * INNER_ + h * DH_;
  bf16x8 af[4][2];
#pragma unroll
  for (int mi = 0; mi < 4; mi++)
#pragma unroll
    for (int ks = 0; ks < 2; ks++)
      af[mi][ks] = *(const bf16x8*)&Q[qbase + (size_t)(mi * 16 + l15) * INNER_ + ks * 32 + lk * 8];
  float racc[4][4] = {};
  for (int j0 = wave * 16; j0 < NK; j0 += 64) {
    const size_t kbase = ((size_t)b * NK + j0 + l15) * INNER_ + h * DH_ + lk * 8;
    bf16x8 b0 = *(const bf16x8*)&Kc[kbase];
    bf16x8 b1 = *(const bf16x8*)&Kc[kbase + 32];
#pragma unroll
    for (int mi = 0; mi < 4; mi++) {
      f32x4 acc = {};
      acc = __builtin_amdgcn_mfma_f32_16x16x32_bf16(af[mi][0], b0, acc, 0, 0, 0);
      acc = __builtin_amdgcn_mfma_f32_16x16x32_bf16(af[mi][1], b1, acc, 0, 0, 0);
#pragma unroll
      for (int r = 0; r < 4; r++) racc[mi][r] += __expf(acc[r] * SCALE_);
    }
  }
#pragma unroll
  for (int o = 1; o < 16; o <<= 1)
#pragma unroll
    for (int mi = 0; mi < 4; mi++)
#pragma unroll
      for (int r = 0; r < 4; r++) racc[mi][r] += __shfl_xor(racc[mi][r], o, 64);
  __shared__ float part[4][64];
  if (l15 == 0)
#pragma unroll
    for (int mi = 0; mi < 4; mi++)
#pragma unroll
      for (int r = 0; r < 4; r++) part[wave][mi * 16 + lk * 4 + r] = racc[mi][r];
  __syncthreads();
  if (t < 64)
    out[((size_t)b * H_ + h) * NQ + i0 + t] = part[0][t] + part[1][t] + part[2][t] + part[3][t];
}

// ---------------- fused attention: 32-i tile, 32-j iter, XCD-pinned, 8 WAVES ----------------
// v6 = v5 (round-10, PASSED) + register diet to end the spill. Round-10 ledger:
// unified cap 128 = acc 64 (AGPR half) + 64 arch; demand ran ~8-16 over -> 73MB
// scratch WRITE + partial Q re-read. Two shaves, math identical:
//  1) tfrag -> LDS (tfS, 1KB; lane-identical across waves, wave 0 writes).
//     P2 reads it per-iter into a transient. Frees 4 always-live regs.
//     lane*16B stride = 2-way bank alias = free (m136).
//  2) 32-bit offset addressing for K (P1) and V (P3): uniform 64-bit base
//     (SGPR) + unsigned lane offset (max 4.2MB) -> saddr+voffset form, frees
//     per-lane 64-bit address pairs (~6-8 regs).
// Pre-committed: if FETCH>300MB or WRITE>150MB again, revert to round-7.
#define MSROW 40
#define MSG   (32 * MSROW + 8)   // 1288 shorts per g; +8 breaks g-stride %32 banks
__global__ __launch_bounds__(512, 4) void fused_attn_kernel(
    const unsigned short* __restrict__ Q, const unsigned short* __restrict__ Kc,
    const unsigned short* __restrict__ Vt, const float* __restrict__ rsum,
    const float* __restrict__ thw,
    float* __restrict__ p0, float* __restrict__ p1,
    float* __restrict__ p2, float* __restrict__ p3,
    int NQ, int NK, int CHUNK) {
  __shared__ unsigned short Pb[4 * 256 * 16];   // 32 KB, quarter = isub + 2*jstrip
  __shared__ unsigned short Ms[16 * MSG];       // 41.2 KB
  __shared__ float lrS[512];                    // [h][i 32] = -ln(rsum)
  __shared__ unsigned short tfS[64 * 8];        // 1 KB: thw B-frag per lane
  int n = blockIdx.x;
  int combo = n & 7;
  int b = combo >> 2, jc = combo & 3;
  int i0 = (n >> 3) * 32;
  float* __restrict__ Op = (jc == 0) ? p0 : (jc == 1) ? p1 : (jc == 2) ? p2 : p3;
  int t = threadIdx.x, lane = t & 63, wave = t >> 6;   // wave 0..7
  int l15 = lane & 15, lk = lane >> 4;

  lrS[t] = -__logf(rsum[((size_t)b * H_ + (t >> 5)) * NQ + i0 + (t & 31)]);

  // thw B-frag -> LDS (values depend only on lane; wave 0 writes for all)
  if (t < 64) {
    int part = lk >> 1, hb = (lk & 1) * 8;
#pragma unroll
    for (int e = 0; e < 8; e++) {
      float a = thw[l15 * H_ + hb + e];
      unsigned short hi = f2bf(a);
      tfS[t * 8 + e] = (part == 0 ? hi : f2bf(a - bf2f(hi)));
    }
  }
  __syncthreads();

  const unsigned short* Qrow = Q + ((size_t)b * NQ + i0 + l15) * INNER_;
  // hoist Q for BOTH heads {2w, 2w+1} via volatile asm loads (non-sinkable)
  bf16x8 qpre[2][2][2];
#pragma unroll
  for (int hh = 0; hh < 2; hh++)
#pragma unroll
    for (int is = 0; is < 2; is++)
#pragma unroll
      for (int kk = 0; kk < 2; kk++) {
        const unsigned short* qp = &Qrow[(size_t)(is * 16) * INNER_
                                         + (wave * 2 + hh) * 64 + kk * 32 + lk * 8];
        asm volatile("global_load_dwordx4 %0, %1, off"
                     : "=v"(qpre[hh][is][kk]) : "v"(qp));
      }
  asm volatile("s_waitcnt vmcnt(0)" ::: "memory");
  __builtin_amdgcn_sched_barrier(0);

  // uniform 64-bit bases for 32-bit offset addressing
  const unsigned short* KcB = Kc + (size_t)b * NK * INNER_;
  const unsigned short* VtB = Vt + (size_t)b * INNER_ * NK;

  // lane-constant Pb write column: granule of 2 shorts at 2w, xor-spread by
  // row bits {2,3} (=l15 bits 2,3) and row bit 6 (=lk bit 0)
  int xsw2 = (((l15 >> 2) & 3) << 1) | (lk & 1);      // 0..7
  int colw = (wave * 2) ^ (xsw2 << 1);                // 0..15, bit0 = 0

  f32x4 acc[16] = {};  // [gi*8 + is*4 + nt]
  const int jbeg = jc * CHUNK;

  for (int js = 0; js < CHUNK; js += 32) {
    int j0 = jbeg + js;
    unsigned kj = (unsigned)(j0 + l15) * INNER_ + lk * 8;
    // ---- phase 1: sim for 2 heads over 32i x 32j; no stage array ----
#pragma unroll
    for (int jp = 0; jp < 2; jp++) {
      unsigned kjj = kj + jp * 16 * INNER_;
      unsigned short* pq = &Pb[jp * 2 * 4096 + colw];
#pragma unroll
      for (int hh = 0; hh < 2; hh++) {
        int h = wave * 2 + hh;
        bf16x8 kb0 = *(const bf16x8*)&KcB[kjj + h * 64];
        bf16x8 kb1 = *(const bf16x8*)&KcB[kjj + h * 64 + 32];
#pragma unroll
        for (int is = 0; is < 2; is++) {
          f32x4 s = {};
          s = __builtin_amdgcn_mfma_f32_16x16x32_bf16(qpre[hh][is][0], kb0, s, 0, 0, 0);
          s = __builtin_amdgcn_mfma_f32_16x16x32_bf16(qpre[hh][is][1], kb1, s, 0, 0, 0);
          f32x4 lr = *(const f32x4*)&lrS[h * 32 + is * 16 + lk * 4];
#pragma unroll
          for (int r = 0; r < 4; r++) {
            int row = (lk * 4 + r) * 16 + l15;
            pq[is * 4096 + row * 16 + hh] = f2bf(__expf(fmaf(s[r], SCALE_, lr[r])));
          }
        }
      }
    }
    __syncthreads();   // bar1: all h-granules of Pb complete
    // ---- phase 2: MFMA mix; wave w -> quarter w&3, p-range (w>>2)*8..+8 ----
    {
      int q = wave & 3, pbase = (wave >> 2) * 8;
      int isub = q & 1, jstrip = q >> 1;
      const unsigned short* pr = &Pb[q * 4096];
      bf16x8 tf = *(const bf16x8*)&tfS[lane * 8];
      int cb = (lk & 1) << 3;
      int xme = ((l15 >> 2) & 3) << 2;   // member bits of the inverse swizzle
#pragma unroll
      for (int p8 = 0; p8 < 8; p8++) {
        int p = pbase + p8;
        int row = p * 16 + l15;
        int xr = xme | (((p >> 2) & 1) << 1);   // inverse swizzle for this row
        union { bf16x8 v; unsigned int u[4]; } U;
        U.u[0] = *(const unsigned int*)&pr[row * 16 + ((cb | 0) ^ xr)];
        U.u[1] = *(const unsigned int*)&pr[row * 16 + ((cb | 2) ^ xr)];
        U.u[2] = *(const unsigned int*)&pr[row * 16 + ((cb | 4) ^ xr)];
        U.u[3] = *(const unsigned int*)&pr[row * 16 + ((cb | 6) ^ xr)];
        f32x4 m = {};
        m = __builtin_amdgcn_mfma_f32_16x16x32_bf16(U.v, tf, m, 0, 0, 0);
        ushort4 o;
        o.x = f2bf(m[0]); o.y = f2bf(m[1]); o.z = f2bf(m[2]); o.w = f2bf(m[3]);
        *(ushort4*)&Ms[l15 * MSG + (isub * 16 + p) * MSROW + jstrip * 16 + lk * 4] = o;
      }
    }
    __syncthreads();   // bar2: Ms complete
    // ---- phase 3: PV (wave owns g = 2w, 2w+1, both isubs) ----
#pragma unroll
    for (int gi = 0; gi < 2; gi++) {
      int g = wave * 2 + gi;
      bf16x8 ma0 = *(const bf16x8*)&Ms[g * MSG + l15 * MSROW + lk * 8];
      bf16x8 ma1 = *(const bf16x8*)&Ms[g * MSG + (16 + l15) * MSROW + lk * 8];
#pragma unroll
      for (int nt = 0; nt < 4; nt++) {
        unsigned voff = (unsigned)(g * 64 + nt * 16 + l15) * NK + j0 + lk * 8;
        bf16x8 v0 = *(const bf16x8*)&VtB[voff];
        acc[gi * 8 + nt]     = __builtin_amdgcn_mfma_f32_16x16x32_bf16(ma0, v0, acc[gi * 8 + nt], 0, 0, 0);
        acc[gi * 8 + 4 + nt] = __builtin_amdgcn_mfma_f32_16x16x32_bf16(ma1, v0, acc[gi * 8 + 4 + nt], 0, 0, 0);
      }
    }
    // no barrier: next P1 writes Pb only (its readers finished before bar2);
    // next Ms writes are fenced by next bar1.
  }
#pragma unroll
  for (int gi = 0; gi < 2; gi++)
#pragma unroll
    for (int is = 0; is < 2; is++)
#pragma unroll
      for (int nt = 0; nt < 4; nt++) {
        int col = (wave * 2 + gi) * 64 + nt * 16 + l15;
#pragma unroll
        for (int r = 0; r < 4; r++)
          Op[((size_t)b * NQ + i0 + is * 16 + lk * 4 + r) * INNER_ + col] = acc[gi * 8 + is * 4 + nt][r];
      }
}

// ---------------- reduce 4 partials + cast to bf16 ----------------
__global__ __launch_bounds__(256) void reduce_cast_kernel(
    const float* __restrict__ p0, const float* __restrict__ p1,
    const float* __restrict__ p2, const float* __restrict__ p3,
    unsigned short* __restrict__ out, int n4) {
  int idx = blockIdx.x * 256 + threadIdx.x;
  if (idx >= n4) return;
  float4 v = ((const float4*)p0)[idx];
  float4 w = ((const float4*)p1)[idx];
  float4 a = ((const float4*)p2)[idx];
  float4 c = ((const float4*)p3)[idx];
  v.x += w.x + a.x + c.x; v.y += w.y + a.y + c.y;
  v.z += w.z + a.z + c.z; v.w += w.w + a.w + c.w;
  ushort4 o;
  o.x = f2bf(v.x); o.y = f2bf(v.y); o.z = f2bf(v.z); o.w = f2bf(v.w);
  ((ushort4*)out)[idx] = o;
}

// ---------------- launch ----------------
extern "C" void kernel_launch(void* const* d_in, const int* in_sizes, int n_in,
                              void* d_out, int out_size, void* d_ws, size_t ws_size,
                              hipStream_t stream) {
  const float* x      = (const float*)d_in[0];
  const float* ctx    = (const float*)d_in[1];
  const float* ln_g   = (const float*)d_in[2];
  const float* ln_b   = (const float*)d_in[3];
  const float* cln_g  = (const float*)d_in[4];
  const float* cln_b  = (const float*)d_in[5];
  const float* W_qk   = (const float*)d_in[6];
  const float* W_cqk  = (const float*)d_in[7];
  const float* W_v    = (const float*)d_in[8];
  const float* W_cv   = (const float*)d_in[9];
  const float* W_out  = (const float*)d_in[10];
  const float* b_out  = (const float*)d_in[11];
  const float* W_cout = (const float*)d_in[12];
  const float* b_cout = (const float*)d_in[13];
  const float* th_w   = (const float*)d_in[14];
  const float* cth_w  = (const float*)d_in[15];

  char* w = (char*)d_ws;
  const size_t SZ_ROW = (size_t)B_ * I_ * DIM_ * 2;   // 8.39 MB
  const size_t SZ_W   = (size_t)DIM_ * INNER_ * 2;    // 2.1 MB
  unsigned short* xn    = (unsigned short*)w; w += SZ_ROW;  // p0 overlay later
  unsigned short* cn    = (unsigned short*)w; w += SZ_ROW;
  unsigned short* WqvX  = (unsigned short*)w; w += 2 * SZ_W;  // [Wqk^T ; Wv^T]
  unsigned short* WqvC  = (unsigned short*)w; w += 2 * SZ_W;  // [Wcqk^T ; Wcv^T]
  unsigned short* Woutt = (unsigned short*)w; w += SZ_W;
  unsigned short* Wcoutt= (unsigned short*)w; w += SZ_W;
  unsigned short* qk    = (unsigned short*)w; w += SZ_ROW;
  unsigned short* ck    = (unsigned short*)w; w += SZ_ROW;
  unsigned short* vv    = (unsigned short*)w; w += SZ_ROW;  // p1 overlay later
  unsigned short* cv    = (unsigned short*)w; w += SZ_ROW;
  unsigned short* vT    = (unsigned short*)w; w += SZ_ROW;
  unsigned short* cvT   = (unsigned short*)w; w += SZ_ROW;
  float* rsum = (float*)w; w += (size_t)B_ * H_ * I_ * 4;
  float* csum = (float*)w; w += (size_t)B_ * H_ * J_ * 4;
  unsigned short* Oh1 = (unsigned short*)w; w += SZ_ROW;
  unsigned short* Oh2 = (unsigned short*)w; w += SZ_ROW;

  // 4 partial buffers (16.78 MB each): p0 over xn+cn (dead after input GEMMs),
  // p1 over vv+cv (dead after transposes), p2/p3 fresh tail.
  const size_t PART = (size_t)B_ * I_ * INNER_ * 4;
  float* p0 = (float*)xn;
  float* p1 = (float*)vv;
  float* p2 = (float*)w;
  float* p3 = (float*)(w + PART);

  dim3 tb(32, 8);
  ln_cast_kernel<<<B_ * I_, 256, 0, stream>>>(x, ln_g, ln_b, xn);
  ln_cast_kernel<<<B_ * J_, 256, 0, stream>>>(ctx, cln_g, cln_b, cn);

  const size_t WOFF = (size_t)DIM_ * INNER_;  // elements
  transpose_cast_f32<<<dim3(32, 32, 1), tb, 0, stream>>>(W_qk,   WqvX,        DIM_, INNER_);
  transpose_cast_f32<<<dim3(32, 32, 1), tb, 0, stream>>>(W_v,    WqvX + WOFF, DIM_, INNER_);
  transpose_cast_f32<<<dim3(32, 32, 1), tb, 0, stream>>>(W_cqk,  WqvC,        DIM_, INNER_);
  transpose_cast_f32<<<dim3(32, 32, 1), tb, 0, stream>>>(W_cv,   WqvC + WOFF, DIM_, INNER_);
  transpose_cast_f32<<<dim3(32, 32, 1), tb, 0, stream>>>(W_out,  Woutt, INNER_, DIM_);
  transpose_cast_f32<<<dim3(32, 32, 1), tb, 0, stream>>>(W_cout, Wcoutt,INNER_, DIM_);

  // fused QKV: one launch, 4 products, 1024 blocks (4/CU)
  gemm_qkv<<<dim3(2 * INNER_ / 128, (B_ * I_) / 128, 2), 256, 0, stream>>>(
      xn, cn, WqvX, WqvC, qk, vv, ck, cv, B_ * I_, DIM_);

  transpose_bf16<<<dim3(INNER_ / 32, I_ / 32, B_), tb, 0, stream>>>(vv, vT, I_, INNER_);
  transpose_bf16<<<dim3(INNER_ / 32, J_ / 32, B_), tb, 0, stream>>>(cv, cvT, J_, INNER_);

  // stats: both dirs + both b, 64-i tiles, 2048 blocks
  stats_kernel<<<dim3(I_ / 64, H_, 4), 256, 0, stream>>>(qk, ck, rsum, csum, I_, J_);

  const int n4 = (B_ * I_ * INNER_) / 4;
  // dir1: softmax over j, rows i  (512 blocks x 512 threads, 8 waves)
  fused_attn_kernel<<<(I_ / 32) * 4 * B_, 512, 0, stream>>>(
      qk, ck, cvT, rsum, th_w, p0, p1, p2, p3, I_, J_, J_ / 4);
  reduce_cast_kernel<<<n4 / 256, 256, 0, stream>>>(p0, p1, p2, p3, Oh1, n4);
  // dir2: softmax over i, rows j
  fused_attn_kernel<<<(J_ / 32) * 4 * B_, 512, 0, stream>>>(
      ck, qk, vT, csum, cth_w, p0, p1, p2, p3, J_, I_, I_ / 4);
  reduce_cast_kernel<<<n4 / 256, 256, 0, stream>>>(p0, p1, p2, p3, Oh2, n4);

  // both output GEMMs in one launch
  gemm_out<<<dim3(DIM_ / 128, (B_ * I_) / 128, 2), 256, 0, stream>>>(
      Oh1, Oh2, Woutt, Wcoutt, b_out, b_cout,
      (float*)d_out, ((float*)d_out) + (size_t)B_ * I_ * DIM_,
      B_ * I_, DIM_, INNER_);
}

// Round 12
// 779.830 us; speedup vs baseline: 1.4942x; 1.4942x over previous
//
#include <hip/hip_runtime.h>
#include <hip/hip_bf16.h>
#include <cstdint>

#define DIM_   1024
#define H_     16
#define DH_    64
#define INNER_ 1024
#define B_     2
#define I_     2048
#define J_     2048
#define SCALE_ 0.125f

using bf16x8 = __attribute__((ext_vector_type(8))) short;
using f32x4  = __attribute__((ext_vector_type(4))) float;

__device__ __forceinline__ unsigned short f2bf(float f) {
  unsigned int u = __float_as_uint(f);
  u = (u + 0x7FFFu + ((u >> 16) & 1u)) >> 16;
  return (unsigned short)u;
}
__device__ __forceinline__ float bf2f(unsigned short h) {
  return __uint_as_float(((unsigned int)h) << 16);
}

// async global->LDS, 16B per lane; LDS dest is wave-uniform base + lane*16
__device__ __forceinline__ void gld16(const unsigned short* g, unsigned short* l) {
  __builtin_amdgcn_global_load_lds(
      (const __attribute__((address_space(1))) unsigned int*)g,
      (__attribute__((address_space(3))) unsigned int*)l, 16, 0, 0);
}

// ---------------- LayerNorm + cast to bf16 ----------------
__global__ __launch_bounds__(256) void ln_cast_kernel(
    const float* __restrict__ in, const float* __restrict__ g,
    const float* __restrict__ bb, unsigned short* __restrict__ out) {
  int row = blockIdx.x;
  int t = threadIdx.x;
  const float4* rp = (const float4*)(in + (size_t)row * DIM_);
  float4 v = rp[t];
  float s  = v.x + v.y + v.z + v.w;
  float ss = v.x * v.x + v.y * v.y + v.z * v.z + v.w * v.w;
  for (int o = 1; o < 64; o <<= 1) {
    s  += __shfl_xor(s, o, 64);
    ss += __shfl_xor(ss, o, 64);
  }
  __shared__ float ls[4], lss[4];
  int wave = t >> 6, lane = t & 63;
  if (lane == 0) { ls[wave] = s; lss[wave] = ss; }
  __syncthreads();
  s  = ls[0] + ls[1] + ls[2] + ls[3];
  ss = lss[0] + lss[1] + lss[2] + lss[3];
  float mu  = s * (1.0f / DIM_);
  float var = ss * (1.0f / DIM_) - mu * mu;
  float rstd = rsqrtf(var + 1e-5f);
  float4 gv = ((const float4*)g)[t];
  float4 bv = ((const float4*)bb)[t];
  ushort4 o4;
  o4.x = f2bf((v.x - mu) * rstd * gv.x + bv.x);
  o4.y = f2bf((v.y - mu) * rstd * gv.y + bv.y);
  o4.z = f2bf((v.z - mu) * rstd * gv.z + bv.z);
  o4.w = f2bf((v.w - mu) * rstd * gv.w + bv.w);
  ((ushort4*)(out + (size_t)row * DIM_))[t] = o4;
}

// ---------------- transpose + cast f32 -> bf16 ----------------
__global__ __launch_bounds__(256) void transpose_cast_f32(
    const float* __restrict__ in, unsigned short* __restrict__ out, int R, int C) {
  __shared__ float tile[32][33];
  int z = blockIdx.z;
  const float* ip = in + (size_t)z * R * C;
  unsigned short* op = out + (size_t)z * R * C;
  int c0 = blockIdx.x * 32, r0 = blockIdx.y * 32;
  int tx = threadIdx.x, ty = threadIdx.y;
  for (int k = 0; k < 4; k++)
    tile[ty * 4 + k][tx] = ip[(size_t)(r0 + ty * 4 + k) * C + c0 + tx];
  __syncthreads();
  for (int k = 0; k < 4; k++)
    op[(size_t)(c0 + ty * 4 + k) * R + r0 + tx] = f2bf(tile[tx][ty * 4 + k]);
}

// ---------------- transpose bf16 -> bf16 ----------------
__global__ __launch_bounds__(256) void transpose_bf16(
    const unsigned short* __restrict__ in, unsigned short* __restrict__ out, int R, int C) {
  __shared__ unsigned short tile[32][33];
  int z = blockIdx.z;
  const unsigned short* ip = in + (size_t)z * R * C;
  unsigned short* op = out + (size_t)z * R * C;
  int c0 = blockIdx.x * 32, r0 = blockIdx.y * 32;
  int tx = threadIdx.x, ty = threadIdx.y;
  for (int k = 0; k < 4; k++)
    tile[ty * 4 + k][tx] = ip[(size_t)(r0 + ty * 4 + k) * C + c0 + tx];
  __syncthreads();
  for (int k = 0; k < 4; k++)
    op[(size_t)(c0 + ty * 4 + k) * R + r0 + tx] = tile[tx][ty * 4 + k];
}

// ---------------- fused QKV GEMM: m97-style global_load_lds staging ----------------
__global__ __launch_bounds__(256) void gemm_qkv(
    const unsigned short* __restrict__ A0, const unsigned short* __restrict__ A1,
    const unsigned short* __restrict__ Bt0, const unsigned short* __restrict__ Bt1,
    unsigned short* __restrict__ qkO0, unsigned short* __restrict__ vO0,
    unsigned short* __restrict__ qkO1, unsigned short* __restrict__ vO1,
    int M, int K) {
  __shared__ unsigned short As[128 * 32];
  __shared__ unsigned short Bs[128 * 32];
  int z = blockIdx.z;
  const unsigned short* A  = z ? A1 : A0;
  const unsigned short* Bt = z ? Bt1 : Bt0;
  unsigned short* qkO = z ? qkO1 : qkO0;
  unsigned short* vO  = z ? vO1 : vO0;
  int t = threadIdx.x;
  int lane = t & 63, wave = t >> 6;
  int m0 = blockIdx.y * 128, n0 = blockIdx.x * 128;
  int wm = (wave >> 1) * 64, wn = (wave & 1) * 64;
  int l15 = lane & 15, lk = lane >> 4;
  int srow = t >> 2, scol = (t & 3) * 8;
  f32x4 acc[4][4] = {};

  for (int k0 = 0; k0 < K; k0 += 32) {
    gld16(&A[(size_t)(m0 + srow) * K + k0 + scol],       &As[wave * 512]);
    gld16(&A[(size_t)(m0 + srow + 64) * K + k0 + scol],  &As[2048 + wave * 512]);
    gld16(&Bt[(size_t)(n0 + srow) * K + k0 + scol],      &Bs[wave * 512]);
    gld16(&Bt[(size_t)(n0 + srow + 64) * K + k0 + scol], &Bs[2048 + wave * 512]);
    __syncthreads();
    bf16x8 af[4], bfr[4];
#pragma unroll
    for (int mi = 0; mi < 4; mi++) af[mi]  = *(const bf16x8*)&As[(wm + mi * 16 + l15) * 32 + lk * 8];
#pragma unroll
    for (int ni = 0; ni < 4; ni++) bfr[ni] = *(const bf16x8*)&Bs[(wn + ni * 16 + l15) * 32 + lk * 8];
#pragma unroll
    for (int mi = 0; mi < 4; mi++)
#pragma unroll
      for (int ni = 0; ni < 4; ni++)
        acc[mi][ni] = __builtin_amdgcn_mfma_f32_16x16x32_bf16(af[mi], bfr[ni], acc[mi][ni], 0, 0, 0);
    __syncthreads();
  }
  unsigned short* dst = (n0 < 1024) ? qkO : vO;
  int nbase = n0 & 1023;
#pragma unroll
  for (int mi = 0; mi < 4; mi++)
#pragma unroll
    for (int ni = 0; ni < 4; ni++) {
      int col = nbase + wn + ni * 16 + l15;
#pragma unroll
      for (int r = 0; r < 4; r++) {
        int row = m0 + wm + mi * 16 + lk * 4 + r;
        dst[(size_t)row * INNER_ + col] = f2bf(acc[mi][ni][r]);
      }
    }
}

// ---------------- output GEMM: z in {dir1, dir2}, f32 + bias; gload_lds staging ----
__global__ __launch_bounds__(256) void gemm_out(
    const unsigned short* __restrict__ A0, const unsigned short* __restrict__ A1,
    const unsigned short* __restrict__ Bt0, const unsigned short* __restrict__ Bt1,
    const float* __restrict__ bias0, const float* __restrict__ bias1,
    float* __restrict__ C0, float* __restrict__ C1,
    int M, int N, int K) {
  __shared__ unsigned short As[128 * 32];
  __shared__ unsigned short Bs[128 * 32];
  int z = blockIdx.z;
  const unsigned short* A  = z ? A1 : A0;
  const unsigned short* Bt = z ? Bt1 : Bt0;
  const float* bias = z ? bias1 : bias0;
  float* Cout = z ? C1 : C0;
  int t = threadIdx.x;
  int lane = t & 63, wave = t >> 6;
  int m0 = blockIdx.y * 128, n0 = blockIdx.x * 128;
  int wm = (wave >> 1) * 64, wn = (wave & 1) * 64;
  int l15 = lane & 15, lk = lane >> 4;
  int srow = t >> 2, scol = (t & 3) * 8;
  f32x4 acc[4][4] = {};

  for (int k0 = 0; k0 < K; k0 += 32) {
    gld16(&A[(size_t)(m0 + srow) * K + k0 + scol],       &As[wave * 512]);
    gld16(&A[(size_t)(m0 + srow + 64) * K + k0 + scol],  &As[2048 + wave * 512]);
    gld16(&Bt[(size_t)(n0 + srow) * K + k0 + scol],      &Bs[wave * 512]);
    gld16(&Bt[(size_t)(n0 + srow + 64) * K + k0 + scol], &Bs[2048 + wave * 512]);
    __syncthreads();
    bf16x8 af[4], bfr[4];
#pragma unroll
    for (int mi = 0; mi < 4; mi++) af[mi]  = *(const bf16x8*)&As[(wm + mi * 16 + l15) * 32 + lk * 8];
#pragma unroll
    for (int ni = 0; ni < 4; ni++) bfr[ni] = *(const bf16x8*)&Bs[(wn + ni * 16 + l15) * 32 + lk * 8];
#pragma unroll
    for (int mi = 0; mi < 4; mi++)
#pragma unroll
      for (int ni = 0; ni < 4; ni++)
        acc[mi][ni] = __builtin_amdgcn_mfma_f32_16x16x32_bf16(af[mi], bfr[ni], acc[mi][ni], 0, 0, 0);
    __syncthreads();
  }
#pragma unroll
  for (int mi = 0; mi < 4; mi++)
#pragma unroll
    for (int ni = 0; ni < 4; ni++) {
      int col = n0 + wn + ni * 16 + l15;
      float bsv = bias[col];
#pragma unroll
      for (int r = 0; r < 4; r++) {
        int row = m0 + wm + mi * 16 + lk * 4 + r;
        Cout[(size_t)row * N + col] = acc[mi][ni][r] + bsv;
      }
    }
}

// ---------------- stats: both dirs + both b in one launch; 64-i tiles ----------------
__global__ __launch_bounds__(256) void stats_kernel(
    const unsigned short* __restrict__ qk, const unsigned short* __restrict__ ck,
    float* __restrict__ rsum, float* __restrict__ csum, int NQ, int NK) {
  int zz = blockIdx.z;
  int b = zz & 1, dir = zz >> 1;
  const unsigned short* Q  = dir ? ck : qk;
  const unsigned short* Kc = dir ? qk : ck;
  float* out = dir ? csum : rsum;
  int h = blockIdx.y, i0 = blockIdx.x * 64;
  int t = threadIdx.x, lane = t & 63, wave = t >> 6;
  int l15 = lane & 15, lk = lane >> 4;
  const size_t qbase = ((size_t)b * NQ + i0) * INNER_ + h * DH_;
  bf16x8 af[4][2];
#pragma unroll
  for (int mi = 0; mi < 4; mi++)
#pragma unroll
    for (int ks = 0; ks < 2; ks++)
      af[mi][ks] = *(const bf16x8*)&Q[qbase + (size_t)(mi * 16 + l15) * INNER_ + ks * 32 + lk * 8];
  float racc[4][4] = {};
  for (int j0 = wave * 16; j0 < NK; j0 += 64) {
    const size_t kbase = ((size_t)b * NK + j0 + l15) * INNER_ + h * DH_ + lk * 8;
    bf16x8 b0 = *(const bf16x8*)&Kc[kbase];
    bf16x8 b1 = *(const bf16x8*)&Kc[kbase + 32];
#pragma unroll
    for (int mi = 0; mi < 4; mi++) {
      f32x4 acc = {};
      acc = __builtin_amdgcn_mfma_f32_16x16x32_bf16(af[mi][0], b0, acc, 0, 0, 0);
      acc = __builtin_amdgcn_mfma_f32_16x16x32_bf16(af[mi][1], b1, acc, 0, 0, 0);
#pragma unroll
      for (int r = 0; r < 4; r++) racc[mi][r] += __expf(acc[r] * SCALE_);
    }
  }
#pragma unroll
  for (int o = 1; o < 16; o <<= 1)
#pragma unroll
    for (int mi = 0; mi < 4; mi++)
#pragma unroll
      for (int r = 0; r < 4; r++) racc[mi][r] += __shfl_xor(racc[mi][r], o, 64);
  __shared__ float part[4][64];
  if (l15 == 0)
#pragma unroll
    for (int mi = 0; mi < 4; mi++)
#pragma unroll
      for (int r = 0; r < 4; r++) part[wave][mi * 16 + lk * 4 + r] = racc[mi][r];
  __syncthreads();
  if (t < 64)
    out[((size_t)b * H_ + h) * NQ + i0 + t] = part[0][t] + part[1][t] + part[2][t] + part[3][t];
}

// ---------------- fused attention: 32-i tile, 32-j iter, XCD-pinned ----------------
// ROUND-7 VERIFIED STATE (784.6 µs total; fused 234.9 µs/dispatch, FETCH 61MB).
// 4 waves, 2 blocks/CU; wave w owns heads 4w..4w+3; whole Q tile in registers
// (fits: 4-wave geometry leaves 128 arch regs beside the 128-AGPR acc);
// K/V chunk L2-resident per XCD; 2 barriers/iter; P3 overlaps next-iter K loads;
// lrS fold (normalize in exponent). 8-wave family (r8-r11) closed: its register
// working set exceeds the 128-unified envelope -> sink/spill every time.
#define MSROW 40
#define MSG   (32 * MSROW + 8)   // 1288 shorts per g; +8 breaks g-stride %32 banks
__global__ __launch_bounds__(256, 2) void fused_attn_kernel(
    const unsigned short* __restrict__ Q, const unsigned short* __restrict__ Kc,
    const unsigned short* __restrict__ Vt, const float* __restrict__ rsum,
    const float* __restrict__ thw,
    float* __restrict__ p0, float* __restrict__ p1,
    float* __restrict__ p2, float* __restrict__ p3,
    int NQ, int NK, int CHUNK) {
  __shared__ unsigned short Pb[4 * 256 * 16];   // 32 KB, quarter = isub + 2*jstrip
  __shared__ unsigned short Ms[16 * MSG];       // 41.2 KB
  __shared__ float lrS[512];                    // [h][i 32] = -ln(rsum)
  int n = blockIdx.x;
  int combo = n & 7;
  int b = combo >> 2, jc = combo & 3;
  int i0 = (n >> 3) * 32;
  float* __restrict__ Op = (jc == 0) ? p0 : (jc == 1) ? p1 : (jc == 2) ? p2 : p3;
  int t = threadIdx.x, lane = t & 63, wave = t >> 6;
  int l15 = lane & 15, lk = lane >> 4;

  lrS[t]       = -__logf(rsum[((size_t)b * H_ + (t >> 5)) * NQ + i0 + (t & 31)]);
  lrS[t + 256] = -__logf(rsum[((size_t)b * H_ + ((t + 256) >> 5)) * NQ + i0 + (t & 31)]);

  // thw B-frag: lane (l15=g, lk): k=lk*8+e; h=(lk&1)*8+e; lk<2 -> hi, else residual
  bf16x8 tfrag;
  {
    int part = lk >> 1, hb = (lk & 1) * 8;
#pragma unroll
    for (int e = 0; e < 8; e++) {
      float a = thw[l15 * H_ + hb + e];
      unsigned short hi = f2bf(a);
      tfrag[e] = (short)(part == 0 ? hi : f2bf(a - bf2f(hi)));
    }
  }
  __syncthreads();

  // ---- hoist the ENTIRE Q tile for this wave's 4 heads into registers ----
  bf16x8 qpre[4][2][2];
#pragma unroll
  for (int hh = 0; hh < 4; hh++)
#pragma unroll
    for (int is = 0; is < 2; is++)
#pragma unroll
      for (int kk = 0; kk < 2; kk++)
        qpre[hh][is][kk] = *(const bf16x8*)&Q[((size_t)b * NQ + i0 + is * 16 + l15) * INNER_
                                              + (wave * 4 + hh) * 64 + kk * 32 + lk * 8];

  f32x4 acc[32] = {};  // [gi*8 + is*4 + nt]
  const int jbeg = jc * CHUNK;

  for (int js = 0; js < CHUNK; js += 32) {
    int j0 = jbeg + js;
    const unsigned short* Kb0 = Kc + ((size_t)b * NK + j0 + l15) * INNER_;
    const unsigned short* Kb1 = Kb0 + (size_t)16 * INNER_;
    // ---- phase 1: sim for 4 heads over full 32i x 32j; Q from regs ----
    unsigned int stage[2][2][4][2];  // [isub][jstrip][r][uint pair]
#pragma unroll
    for (int hh = 0; hh < 4; hh++) {
      int h = wave * 4 + hh;
      bf16x8 kb00 = *(const bf16x8*)&Kb0[h * 64 + lk * 8];
      bf16x8 kb01 = *(const bf16x8*)&Kb0[h * 64 + 32 + lk * 8];
      bf16x8 kb10 = *(const bf16x8*)&Kb1[h * 64 + lk * 8];
      bf16x8 kb11 = *(const bf16x8*)&Kb1[h * 64 + 32 + lk * 8];
#pragma unroll
      for (int is = 0; is < 2; is++) {
        f32x4 s0 = {}, s1 = {};
        s0 = __builtin_amdgcn_mfma_f32_16x16x32_bf16(qpre[hh][is][0], kb00, s0, 0, 0, 0);
        s0 = __builtin_amdgcn_mfma_f32_16x16x32_bf16(qpre[hh][is][1], kb01, s0, 0, 0, 0);
        s1 = __builtin_amdgcn_mfma_f32_16x16x32_bf16(qpre[hh][is][0], kb10, s1, 0, 0, 0);
        s1 = __builtin_amdgcn_mfma_f32_16x16x32_bf16(qpre[hh][is][1], kb11, s1, 0, 0, 0);
        f32x4 lr = *(const f32x4*)&lrS[h * 32 + is * 16 + lk * 4];
#pragma unroll
        for (int r = 0; r < 4; r++) {
          unsigned int b0 = f2bf(__expf(fmaf(s0[r], SCALE_, lr[r])));
          unsigned int b1 = f2bf(__expf(fmaf(s1[r], SCALE_, lr[r])));
          if (hh & 1) { stage[is][0][r][hh >> 1] |= b0 << 16; stage[is][1][r][hh >> 1] |= b1 << 16; }
          else        { stage[is][0][r][hh >> 1]  = b0;       stage[is][1][r][hh >> 1]  = b1; }
        }
      }
    }
    // write P^T slices: quarter (isub,jstrip), rows pos = im*16+jl, h-cols wave*4..+3
#pragma unroll
    for (int is = 0; is < 2; is++)
#pragma unroll
      for (int jp = 0; jp < 2; jp++)
#pragma unroll
        for (int r = 0; r < 4; r++) {
          int row = (lk * 4 + r) * 16 + l15;          // pos = im*16 + jl
          int col = (wave * 4) ^ ((row & 1) << 3);    // xor-swizzle banks
          uint2 u = { stage[is][jp][r][0], stage[is][jp][r][1] };
          *(uint2*)&Pb[(is + jp * 2) * 256 * 16 + row * 16 + col] = u;
        }
    __syncthreads();   // bar1: all h-slices of Pb complete
    // ---- phase 2: MFMA mix; wave handles quarter (isub=w&1, jstrip=w>>1) ----
    {
      int isub = wave & 1, jstrip = wave >> 1;
      const unsigned short* pr = &Pb[(isub + jstrip * 2) * 256 * 16];
#pragma unroll
      for (int p = 0; p < 16; p++) {
        int row = p * 16 + l15;
        int col = ((lk & 1) << 3) ^ ((row & 1) << 3);
        bf16x8 af = *(const bf16x8*)&pr[row * 16 + col];
        f32x4 m = {};
        m = __builtin_amdgcn_mfma_f32_16x16x32_bf16(af, tfrag, m, 0, 0, 0);
        ushort4 o;
        o.x = f2bf(m[0]); o.y = f2bf(m[1]); o.z = f2bf(m[2]); o.w = f2bf(m[3]);
        *(ushort4*)&Ms[l15 * MSG + (isub * 16 + p) * MSROW + jstrip * 16 + lk * 4] = o;
      }
    }
    __syncthreads();   // bar2: Ms complete
    // ---- phase 3: PV (wave owns g = wave*4..+3, both isubs) ----
#pragma unroll
    for (int gi = 0; gi < 4; gi++) {
      int g = wave * 4 + gi;
      bf16x8 ma0 = *(const bf16x8*)&Ms[g * MSG + l15 * MSROW + lk * 8];
      bf16x8 ma1 = *(const bf16x8*)&Ms[g * MSG + (16 + l15) * MSROW + lk * 8];
#pragma unroll
      for (int nt = 0; nt < 4; nt++) {
        const size_t vb = ((size_t)b * INNER_ + g * 64 + nt * 16 + l15) * NK + j0 + lk * 8;
        bf16x8 v0 = *(const bf16x8*)&Vt[vb];
        acc[gi * 8 + nt]     = __builtin_amdgcn_mfma_f32_16x16x32_bf16(ma0, v0, acc[gi * 8 + nt], 0, 0, 0);
        acc[gi * 8 + 4 + nt] = __builtin_amdgcn_mfma_f32_16x16x32_bf16(ma1, v0, acc[gi * 8 + 4 + nt], 0, 0, 0);
      }
    }
    // no barrier: next P1 writes Pb only (its readers finished before bar2);
    // next Ms writes are fenced by next bar1.
  }
#pragma unroll
  for (int gi = 0; gi < 4; gi++)
#pragma unroll
    for (int is = 0; is < 2; is++)
#pragma unroll
      for (int nt = 0; nt < 4; nt++) {
        int col = (wave * 4 + gi) * 64 + nt * 16 + l15;
#pragma unroll
        for (int r = 0; r < 4; r++)
          Op[((size_t)b * NQ + i0 + is * 16 + lk * 4 + r) * INNER_ + col] = acc[gi * 8 + is * 4 + nt][r];
      }
}

// ---------------- reduce 4 partials + cast to bf16 ----------------
__global__ __launch_bounds__(256) void reduce_cast_kernel(
    const float* __restrict__ p0, const float* __restrict__ p1,
    const float* __restrict__ p2, const float* __restrict__ p3,
    unsigned short* __restrict__ out, int n4) {
  int idx = blockIdx.x * 256 + threadIdx.x;
  if (idx >= n4) return;
  float4 v = ((const float4*)p0)[idx];
  float4 w = ((const float4*)p1)[idx];
  float4 a = ((const float4*)p2)[idx];
  float4 c = ((const float4*)p3)[idx];
  v.x += w.x + a.x + c.x; v.y += w.y + a.y + c.y;
  v.z += w.z + a.z + c.z; v.w += w.w + a.w + c.w;
  ushort4 o;
  o.x = f2bf(v.x); o.y = f2bf(v.y); o.z = f2bf(v.z); o.w = f2bf(v.w);
  ((ushort4*)out)[idx] = o;
}

// ---------------- launch ----------------
extern "C" void kernel_launch(void* const* d_in, const int* in_sizes, int n_in,
                              void* d_out, int out_size, void* d_ws, size_t ws_size,
                              hipStream_t stream) {
  const float* x      = (const float*)d_in[0];
  const float* ctx    = (const float*)d_in[1];
  const float* ln_g   = (const float*)d_in[2];
  const float* ln_b   = (const float*)d_in[3];
  const float* cln_g  = (const float*)d_in[4];
  const float* cln_b  = (const float*)d_in[5];
  const float* W_qk   = (const float*)d_in[6];
  const float* W_cqk  = (const float*)d_in[7];
  const float* W_v    = (const float*)d_in[8];
  const float* W_cv   = (const float*)d_in[9];
  const float* W_out  = (const float*)d_in[10];
  const float* b_out  = (const float*)d_in[11];
  const float* W_cout = (const float*)d_in[12];
  const float* b_cout = (const float*)d_in[13];
  const float* th_w   = (const float*)d_in[14];
  const float* cth_w  = (const float*)d_in[15];

  char* w = (char*)d_ws;
  const size_t SZ_ROW = (size_t)B_ * I_ * DIM_ * 2;   // 8.39 MB
  const size_t SZ_W   = (size_t)DIM_ * INNER_ * 2;    // 2.1 MB
  unsigned short* xn    = (unsigned short*)w; w += SZ_ROW;  // p0 overlay later
  unsigned short* cn    = (unsigned short*)w; w += SZ_ROW;
  unsigned short* WqvX  = (unsigned short*)w; w += 2 * SZ_W;  // [Wqk^T ; Wv^T]
  unsigned short* WqvC  = (unsigned short*)w; w += 2 * SZ_W;  // [Wcqk^T ; Wcv^T]
  unsigned short* Woutt = (unsigned short*)w; w += SZ_W;
  unsigned short* Wcoutt= (unsigned short*)w; w += SZ_W;
  unsigned short* qk    = (unsigned short*)w; w += SZ_ROW;
  unsigned short* ck    = (unsigned short*)w; w += SZ_ROW;
  unsigned short* vv    = (unsigned short*)w; w += SZ_ROW;  // p1 overlay later
  unsigned short* cv    = (unsigned short*)w; w += SZ_ROW;
  unsigned short* vT    = (unsigned short*)w; w += SZ_ROW;
  unsigned short* cvT   = (unsigned short*)w; w += SZ_ROW;
  float* rsum = (float*)w; w += (size_t)B_ * H_ * I_ * 4;
  float* csum = (float*)w; w += (size_t)B_ * H_ * J_ * 4;
  unsigned short* Oh1 = (unsigned short*)w; w += SZ_ROW;
  unsigned short* Oh2 = (unsigned short*)w; w += SZ_ROW;

  // 4 partial buffers (16.78 MB each): p0 over xn+cn (dead after input GEMMs),
  // p1 over vv+cv (dead after transposes), p2/p3 fresh tail.
  const size_t PART = (size_t)B_ * I_ * INNER_ * 4;
  float* p0 = (float*)xn;
  float* p1 = (float*)vv;
  float* p2 = (float*)w;
  float* p3 = (float*)(w + PART);

  dim3 tb(32, 8);
  ln_cast_kernel<<<B_ * I_, 256, 0, stream>>>(x, ln_g, ln_b, xn);
  ln_cast_kernel<<<B_ * J_, 256, 0, stream>>>(ctx, cln_g, cln_b, cn);

  const size_t WOFF = (size_t)DIM_ * INNER_;  // elements
  transpose_cast_f32<<<dim3(32, 32, 1), tb, 0, stream>>>(W_qk,   WqvX,        DIM_, INNER_);
  transpose_cast_f32<<<dim3(32, 32, 1), tb, 0, stream>>>(W_v,    WqvX + WOFF, DIM_, INNER_);
  transpose_cast_f32<<<dim3(32, 32, 1), tb, 0, stream>>>(W_cqk,  WqvC,        DIM_, INNER_);
  transpose_cast_f32<<<dim3(32, 32, 1), tb, 0, stream>>>(W_cv,   WqvC + WOFF, DIM_, INNER_);
  transpose_cast_f32<<<dim3(32, 32, 1), tb, 0, stream>>>(W_out,  Woutt, INNER_, DIM_);
  transpose_cast_f32<<<dim3(32, 32, 1), tb, 0, stream>>>(W_cout, Wcoutt,INNER_, DIM_);

  // fused QKV: one launch, 4 products, 1024 blocks (4/CU)
  gemm_qkv<<<dim3(2 * INNER_ / 128, (B_ * I_) / 128, 2), 256, 0, stream>>>(
      xn, cn, WqvX, WqvC, qk, vv, ck, cv, B_ * I_, DIM_);

  transpose_bf16<<<dim3(INNER_ / 32, I_ / 32, B_), tb, 0, stream>>>(vv, vT, I_, INNER_);
  transpose_bf16<<<dim3(INNER_ / 32, J_ / 32, B_), tb, 0, stream>>>(cv, cvT, J_, INNER_);

  // stats: both dirs + both b, 64-i tiles, 2048 blocks
  stats_kernel<<<dim3(I_ / 64, H_, 4), 256, 0, stream>>>(qk, ck, rsum, csum, I_, J_);

  const int n4 = (B_ * I_ * INNER_) / 4;
  // dir1: softmax over j, rows i
  fused_attn_kernel<<<(I_ / 32) * 4 * B_, 256, 0, stream>>>(
      qk, ck, cvT, rsum, th_w, p0, p1, p2, p3, I_, J_, J_ / 4);
  reduce_cast_kernel<<<n4 / 256, 256, 0, stream>>>(p0, p1, p2, p3, Oh1, n4);
  // dir2: softmax over i, rows j
  fused_attn_kernel<<<(J_ / 32) * 4 * B_, 256, 0, stream>>>(
      ck, qk, vT, csum, cth_w, p0, p1, p2, p3, J_, I_, I_ / 4);
  reduce_cast_kernel<<<n4 / 256, 256, 0, stream>>>(p0, p1, p2, p3, Oh2, n4);

  // both output GEMMs in one launch
  gemm_out<<<dim3(DIM_ / 128, (B_ * I_) / 128, 2), 256, 0, stream>>>(
      Oh1, Oh2, Woutt, Wcoutt, b_out, b_cout,
      (float*)d_out, ((float*)d_out) + (size_t)B_ * I_ * DIM_,
      B_ * I_, DIM_, INNER_);
}